// Round 1
// 3500.834 us; speedup vs baseline: 1.2838x; 1.2838x over previous
//
#include <hip/hip_runtime.h>
#include <cstdint>
#include <cstddef>

// ---------------- problem dims ----------------
#define TSTEPS 256
#define BATCH  64
#define OBSD   512
#define HIDD   1024
#define NACT   128
#define TOK    (TSTEPS*BATCH)   // 16384

// fp32 output element offsets
static constexpr size_t O_PROBS = 0;
static constexpr size_t O_LOGPA = (size_t)TOK * NACT;
static constexpr size_t O_ENT   = O_LOGPA + TOK;
static constexpr size_t O_VAL   = O_ENT + TOK;
static constexpr size_t O_HT    = O_VAL + TOK;
static constexpr size_t O_CT    = O_HT + (size_t)BATCH * HIDD;

// bf16 weight/activation pool offsets (elements)
static constexpr size_t OX     = 0;
static constexpr size_t OCOVH  = 8388608;
static constexpr size_t OSNW1  = 10485760;
static constexpr size_t OSNW2  = 11010048;
static constexpr size_t OWIH   = 12058624;
static constexpr size_t OWHH   = 16252928;
static constexpr size_t OACW1  = 20447232;   // ac|cw|cr contiguous -> one N=3072 GEMM
static constexpr size_t OCWW1  = 21495808;
static constexpr size_t OCRW1  = 22544384;
static constexpr size_t OACW2  = 23592960;
static constexpr size_t OCWW2  = 23724032;
static constexpr size_t OCOVW1 = 23855104;
static constexpr size_t OCOVW2 = 23986176;
static constexpr size_t OCRW2  = 24117248;
static constexpr size_t WBUFSZ = 24118272;

using bf16x8 = __attribute__((ext_vector_type(8))) short;
using f32x4  = __attribute__((ext_vector_type(4))) float;

// ---------------- device buffers (all resolved in device code) ----------------
__device__ __align__(16) unsigned short g_wbuf[WBUFSZ];
__device__ __align__(16) unsigned short g_hid1[(size_t)TOK*HIDD];
__device__ __align__(16) unsigned short g_hid [(size_t)TOK*HIDD];
__device__ __align__(16) float          g_xgf [(size_t)TOK*4*HIDD];
__device__ __align__(16) unsigned short g_hid2[(size_t)64*TOK*16];   // blocked hidden [cb][token][16]
__device__ __align__(16) unsigned short g_t3[(size_t)TOK*3*HIDD];    // [TOK][3072] ac|cw|cr
__device__ __align__(16) unsigned short g_aco[(size_t)TOK*NACT];
__device__ __align__(16) unsigned short g_cwo[(size_t)TOK*NACT];
__device__ __align__(16) unsigned short g_covo[(size_t)TOK*NACT];
__device__ __align__(16) unsigned short g_hp2[2*64*1024];            // blocked h ping-pong [buf][cb][row][16]
__device__ float g_val[TOK];
__device__ float g_ht[BATCH*HIDD];
__device__ float g_ct[BATCH*HIDD];
__device__ int g_isf32;
// flag-based step barrier: one monotonic epoch flag per WG.
// Values persist across launches/graph replays; g_fepoch is bumped by +512
// each launch (detect_dtype) so every launch's targets exceed all stale values.
__device__ unsigned g_flags[64];
__device__ unsigned g_fepoch;

__device__ __forceinline__ unsigned short* dev_buf(int id){
  switch(id){
    case 1:  return g_hid1;
    case 2:  return g_hid;
    case 3:  return g_hid2;
    case 4:  return g_t3;
    case 5:  return g_aco;
    case 6:  return g_cwo;
    case 7:  return g_covo;
    case 8:  return (unsigned short*)g_xgf;
    case 9:  return g_t3 + 1024;          // cw slice (row-interleaved, lda 3072)
    case 10: return g_t3 + 2048;          // cr slice
    case 11: return g_wbuf + OX;
    case 12: return g_wbuf + OCOVH;
    case 13: return g_wbuf + OSNW1;
    case 14: return g_wbuf + OSNW2;
    case 15: return g_wbuf + OWIH;
    case 16: return g_wbuf + OWHH;
    case 17: return g_wbuf + OACW1;       // 3072-row fused head weight
    case 20: return g_wbuf + OACW2;
    case 21: return g_wbuf + OCWW2;
    case 22: return g_wbuf + OCOVW1;
    case 23: return g_wbuf + OCOVW2;
    case 24: return g_wbuf + OCRW2;
    default: return nullptr;
  }
}

// ---------------- helpers ----------------
__device__ __forceinline__ float b2f(unsigned short u){
  unsigned int x = ((unsigned int)u) << 16;
  return __builtin_bit_cast(float, x);
}
__device__ __forceinline__ unsigned short f2b(float f){
  unsigned int u = __builtin_bit_cast(unsigned int, f);
  u += 0x7FFFu + ((u >> 16) & 1u);
  return (unsigned short)(u >> 16);
}
__device__ __forceinline__ float ldmix(const void* p, size_t i){
  return g_isf32 ? ((const float*)p)[i] : b2f(((const unsigned short*)p)[i]);
}
__device__ __forceinline__ float ldsel(bool f32, const void* p, size_t i){
  return f32 ? ((const float*)p)[i] : b2f(((const unsigned short*)p)[i]);
}
__device__ __forceinline__ float sigm(float x){ return 1.f/(1.f + __expf(-x)); }
__device__ __forceinline__ float tanh_f(float x){ float e = __expf(2.f*x); return 1.f - 2.f/(e + 1.f); }

__device__ __forceinline__ void gld16(const unsigned short* g, unsigned short* l){
  __builtin_amdgcn_global_load_lds(
      (__attribute__((address_space(1))) void*)(uintptr_t)g,
      (__attribute__((address_space(3))) void*)l,
      16, 0, 0);
}

// single-round flag wait: each wave's 64 lanes poll the 64 WG flags with
// RELAXED agent loads (sc1, reads the coherent point, NO per-poll L2 inval),
// then exactly one acquire fence (buffer_inv) before touching h data.
__device__ __forceinline__ void wait_flags(unsigned tgt){
  const int ln = threadIdx.x & 63;
  unsigned f = __hip_atomic_load(&g_flags[ln], __ATOMIC_RELAXED, __HIP_MEMORY_SCOPE_AGENT);
  while (!__all((int)(f >= tgt))){
    __builtin_amdgcn_s_sleep(2);
    f = __hip_atomic_load(&g_flags[ln], __ATOMIC_RELAXED, __HIP_MEMORY_SCOPE_AGENT);
  }
  __builtin_amdgcn_fence(__ATOMIC_ACQUIRE, "agent");
}

// ---------------- dtype detect (+ per-launch flag-epoch bump) ----------------
__global__ __launch_bounds__(256) void detect_dtype(const unsigned short* x){
  __shared__ int cnt;
  if (threadIdx.x == 0) cnt = 0;
  __syncthreads();
  int c = 0;
  for (int i = threadIdx.x; i < 4096; i += 256){
    float f = b2f(x[2*i]);
    if (!(fabsf(f) < 1e10f)) c++;
  }
  atomicAdd(&cnt, c);
  __syncthreads();
  if (threadIdx.x == 0){
    g_isf32 = (cnt > 64) ? 1 : 0;
    g_fepoch += 512;   // > max per-launch flag advance (TSTEPS+2), keeps epochs monotonic
  }
}

// ---------------- convert 14 arrays into g_wbuf (bf16) ----------------
__global__ __launch_bounds__(256) void cvt_all(
    const void* s0, const void* s1, const void* s2, const void* s3,
    const void* s4, const void* s5, const void* s6, const void* s7,
    const void* s8, const void* s9, const void* s10, const void* s11,
    const void* s12, const void* s13)
{
  const void* src; size_t off; int n;
  switch (blockIdx.y){
    case 0:  src=s0;  off=OX;     n=TOK*OBSD;  break;
    case 1:  src=s1;  off=OCOVH;  n=TOK*NACT;  break;
    case 2:  src=s2;  off=OSNW1;  n=HIDD*OBSD; break;
    case 3:  src=s3;  off=OSNW2;  n=HIDD*HIDD; break;
    case 4:  src=s4;  off=OWIH;   n=4*HIDD*HIDD; break;
    case 5:  src=s5;  off=OWHH;   n=4*HIDD*HIDD; break;
    case 6:  src=s6;  off=OACW1;  n=HIDD*HIDD; break;
    case 7:  src=s7;  off=OCWW1;  n=HIDD*HIDD; break;
    case 8:  src=s8;  off=OCRW1;  n=HIDD*HIDD; break;
    case 9:  src=s9;  off=OACW2;  n=NACT*HIDD; break;
    case 10: src=s10; off=OCWW2;  n=NACT*HIDD; break;
    case 11: src=s11; off=OCOVW1; n=HIDD*NACT; break;
    case 12: src=s12; off=OCOVW2; n=NACT*HIDD; break;
    default: src=s13; off=OCRW2;  n=HIDD;      break;
  }
  const bool f32 = (g_isf32 != 0);
  unsigned short* dst = g_wbuf + off;
  const int stride = gridDim.x * 256;
  for (int i = blockIdx.x*256 + threadIdx.x; i < n; i += stride){
    float v = f32 ? ((const float*)src)[i] : b2f(((const unsigned short*)src)[i]);
    dst[i] = f2b(v);
  }
}

// ---------------- tiled MFMA GEMM: C = act(A @ W^T + bias) ----------------
// ablk: A is blocked [cb][row][16] (g_hid2). bmode: 3-way bias select by col/1024.
__global__ __launch_bounds__(256) void gemm_bt(
    int a_id, int lda, int ablk, int w_id, int K,
    const void* __restrict__ b1, const void* __restrict__ b2, const void* __restrict__ b3,
    int bmode, int c_id, int ldc, int act, int cmode)
{
  __shared__ unsigned short sA[128*32];
  __shared__ unsigned short sB[128*32];
  const unsigned short* A = dev_buf(a_id);
  const unsigned short* W = dev_buf(w_id);
  void* C = dev_buf(c_id);

  const int tid  = threadIdx.x;
  const int wv   = tid >> 6, ln = tid & 63;
  const int quad = ln >> 4, l16 = ln & 15;
  const long bm = (long)blockIdx.y * 128, bn = (long)blockIdx.x * 128;
  const int wr = (wv >> 1) * 64, wc = (wv & 1) * 64;

  const f32x4 zf = {0.f, 0.f, 0.f, 0.f};
  f32x4 acc[4][4];
#pragma unroll
  for (int i = 0; i < 4; i++)
#pragma unroll
    for (int j = 0; j < 4; j++) acc[i][j] = zf;

  const int srow = wv*32 + (ln >> 2);
  const int scol = (ln & 3) * 8;
  const unsigned short* gA = A + (bm + srow)*(long)lda + scol;
  const unsigned short* gB = W + (bn + srow)*(long)K   + scol;
  unsigned short* lA = &sA[(wv*32)*32];
  unsigned short* lB = &sB[(wv*32)*32];

  for (int k0 = 0; k0 < K; k0 += 32){
    __syncthreads();
    if (ablk){
      const int kk = k0 + scol;
      const long cbase = (long)(kk >> 4) * ((long)TOK*16) + (kk & 15);
      gld16(A + cbase + (bm + srow)*16,      lA);
      gld16(A + cbase + (bm + srow + 16)*16, lA + 16*32);
    } else {
      gld16(gA + k0,                lA);
      gld16(gA + k0 + 16*(long)lda, lA + 16*32);
    }
    gld16(gB + k0,               lB);
    gld16(gB + k0 + 16*(long)K,  lB + 16*32);
    __syncthreads();
    bf16x8 af[4], bfr[4];
#pragma unroll
    for (int i = 0; i < 4; i++) af[i]  = *(const bf16x8*)&sA[(wr + 16*i + l16)*32 + quad*8];
#pragma unroll
    for (int j = 0; j < 4; j++) bfr[j] = *(const bf16x8*)&sB[(wc + 16*j + l16)*32 + quad*8];
#pragma unroll
    for (int i = 0; i < 4; i++)
#pragma unroll
      for (int j = 0; j < 4; j++)
        acc[i][j] = __builtin_amdgcn_mfma_f32_16x16x32_bf16(af[i], bfr[j], acc[i][j], 0, 0, 0);
  }

#pragma unroll
  for (int j = 0; j < 4; j++){
    const long col = bn + wc + 16*j + l16;
    float bb;
    if (bmode){
      const void* bp = (col < 1024) ? b1 : (col < 2048) ? b2 : b3;
      bb = ldmix(bp, col & 1023);
    } else {
      bb = (b1 ? ldmix(b1, col) : 0.f) + (b2 ? ldmix(b2, col) : 0.f);
    }
#pragma unroll
    for (int i = 0; i < 4; i++){
#pragma unroll
      for (int r = 0; r < 4; r++){
        const long row = bm + wr + 16*i + quad*4 + r;   // C/D: col=lane&15, row=quad*4+reg
        float v = acc[i][j][r] + bb;
        if (act) v = tanh_f(v);
        if (cmode) ((float*)C)[row*(long)ldc + col] = v;
        else ((unsigned short*)C)[row*(long)ldc + col] = f2b(v);
      }
    }
  }
}

// ---------------- persistent LSTM scan (K-split, LDS-staged h, flag barrier) ----------------
// 64 WGs; WG cb owns h cols [16cb,16cb+16). Wave wv owns K-quarter [256wv,256wv+256)
// and computes partial preacts for ALL 4 gates (w_hh quarter in 128 VGPRs).
// Per step: one-sided flag wait (no RMW barrier) -> one acquire fence ->
// global_load_lds stages the wave's 32KB h quarter (all loads in flight at once)
// -> MFMA from LDS -> partial slabs overlay the wave's own LDS h region ->
// cross-wave LDS reduce -> cell update -> sc1 h stores -> release flag.
// xg/done for the NEXT step are prefetched into registers before the wait.
__global__ __launch_bounds__(256, 1) void lstm_scan(
    const void* __restrict__ done_p,
    const void* __restrict__ h0_p,
    const void* __restrict__ c0_p)
{
  // 128 KB: wave wv's h K-quarter lives at [wv*16384, +16384) elements.
  // After the MFMA phase consumed it, the wave's 4 partial slabs (20 KB)
  // overlay the SAME region (only this wave ever reads its h region, so no
  // extra barrier is needed before the overlay writes).
  __shared__ __align__(16) unsigned short sH[65536];
  float* sPf = (float*)sH;   // slab view: wave w2 at float offset w2*8192

  const int tid  = threadIdx.x;
  const int wv   = tid >> 6, ln = tid & 63;
  const int quad = ln >> 4, l16 = ln & 15;
  const int cb   = blockIdx.x;
  const int col0 = cb * 16;
  const int grow = tid >> 2;           // gate-phase row
  const int gcol = (tid & 3) * 4;
  const bool isf32 = (g_isf32 != 0);
  const unsigned fbase = g_fepoch;     // per-launch monotonic epoch base

  // cell state in registers
  float cst[4];
#pragma unroll
  for (int j = 0; j < 4; j++) cst[j] = ldsel(isf32, c0_p, grow*HIDD + col0 + gcol + j);

  // h0 -> blocked ping buffer (own block), masked by done[0]
  for (int e = tid; e < 1024; e += 256){
    int row = e >> 4, col = e & 15;
    float d0 = ldsel(isf32, done_p, row);
    float h0 = (d0 != 0.f) ? 0.f : ldsel(isf32, h0_p, row*HIDD + col0 + col);
    g_hp2[cb*1024 + e] = f2b(h0);
  }

  // preload w_hh K-quarter for all 4 gates: wreg[g][i], k = wv*256 + i*32 + quad*8
  const unsigned short* wbase = g_wbuf + OWHH;
  bf16x8 wreg[4][8];
#pragma unroll
  for (int g = 0; g < 4; g++)
#pragma unroll
    for (int i = 0; i < 8; i++)
      wreg[g][i] = *(const bf16x8*)&wbase[(size_t)(g*HIDD + col0 + l16)*HIDD + wv*256 + i*32 + quad*8];

  // prefetch step-0 inputs into registers
  float4 xg0, xg1, xg2, xg3;
  {
    const float* xr = &g_xgf[(size_t)grow*4096 + col0 + gcol];
    xg0 = *(const float4*)(xr);
    xg1 = *(const float4*)(xr + 1024);
    xg2 = *(const float4*)(xr + 2048);
    xg3 = *(const float4*)(xr + 3072);
  }
  float dcur = ldsel(isf32, done_p, grow);                 // done[0]
  float dnxt = ldsel(isf32, done_p, BATCH + grow);         // done[1] (TSTEPS>1)

  // publish h0: RELEASE store flushes this WG's dirty (plain) h0 lines to the
  // coherent point before the flag becomes visible.
  __syncthreads();
  if (tid == 0)
    __hip_atomic_store(&g_flags[cb], fbase + 1, __ATOMIC_RELEASE, __HIP_MEMORY_SCOPE_AGENT);

  const f32x4 zf = {0.f, 0.f, 0.f, 0.f};

  for (int s = 0; s < TSTEPS; s++){
    // wait until every WG has published h_s (flag >= fbase+s+1); this also
    // guarantees everyone finished READING buf[(s+1)&1], so writing hn below
    // is overwrite-safe. One acquire fence (L2 inval) per step.
    wait_flags(fbase + (unsigned)s + 1u);

    const unsigned short* hb = g_hp2 + (s & 1)*65536;
    unsigned short*       hn = g_hp2 + ((s + 1) & 1)*65536;

    // stage this wave's 32KB h K-quarter into LDS: 32 x 1KB async direct-to-LDS
    // loads, zero VGPR cost, all outstanding at once (latency paid once).
    {
      const unsigned short* src = hb + wv*16384 + ln*8;
      unsigned short* dstb = sH + wv*16384;     // wave-uniform base; HW adds lane*16B
#pragma unroll
      for (int c2 = 0; c2 < 32; c2++)
        gld16(src + c2*512, dstb + c2*512);
    }
    asm volatile("s_waitcnt vmcnt(0)" ::: "memory");

    // MFMA phase: fragments from LDS (same blocked addressing as global layout)
    const unsigned short* hq = sH + wv*16384 + (quad >> 1)*1024 + l16*16 + (quad & 1)*8;
    f32x4 acc[4][4];   // [gate][row-tile]
#pragma unroll
    for (int g = 0; g < 4; g++)
#pragma unroll
      for (int rt = 0; rt < 4; rt++) acc[g][rt] = zf;
#pragma unroll
    for (int i = 0; i < 8; i++){
      bf16x8 af[4];
#pragma unroll
      for (int rt = 0; rt < 4; rt++)
        af[rt] = *(const bf16x8*)(hq + i*2048 + rt*256);
#pragma unroll
      for (int rt = 0; rt < 4; rt++)
#pragma unroll
        for (int g = 0; g < 4; g++)
          acc[g][rt] = __builtin_amdgcn_mfma_f32_16x16x32_bf16(af[rt], wreg[g][i], acc[g][rt], 0, 0, 0);
    }
    // write partial slabs into THIS wave's own (already-consumed) LDS region
#pragma unroll
    for (int g = 0; g < 4; g++)
#pragma unroll
      for (int rt = 0; rt < 4; rt++)
#pragma unroll
        for (int r = 0; r < 4; r++)
          sPf[wv*8192 + (g*64 + 16*rt + quad*4 + r)*20 + l16] = acc[g][rt][r];
    __syncthreads();

    // gate phase: sum 4 K-partials per gate, then LSTM cell update
    float4 pg[4];
#pragma unroll
    for (int g = 0; g < 4; g++){
      float4 p = {0.f, 0.f, 0.f, 0.f};
#pragma unroll
      for (int w2 = 0; w2 < 4; w2++){
        float4 t = *(const float4*)&sPf[w2*8192 + (g*64 + grow)*20 + gcol];
        p.x += t.x; p.y += t.y; p.z += t.z; p.w += t.w;
      }
      pg[g] = p;
    }
    const bool last = (s == TSTEPS-1);
    unsigned short hs[4];
#pragma unroll
    for (int j = 0; j < 4; j++){
      float iv = sigm (((const float*)&pg[0])[j] + ((const float*)&xg0)[j]);
      float fv = sigm (((const float*)&pg[1])[j] + ((const float*)&xg1)[j]);
      float gv = tanh_f(((const float*)&pg[2])[j] + ((const float*)&xg2)[j]);
      float ov = sigm (((const float*)&pg[3])[j] + ((const float*)&xg3)[j]);
      float cp = (dcur != 0.f) ? 0.f : cst[j];
      float c  = fv*cp + iv*gv;
      float h  = ov * tanh_f(c);
      cst[j] = c;
      hs[j] = f2b(h);
      if (last){
        g_ht[grow*HIDD + col0 + gcol + j] = h;
        g_ct[grow*HIDD + col0 + gcol + j] = c;
      }
    }
    // next-h: pre-masked by done[s+1], write-through (agent scope, sc1)
    unsigned v0 = (unsigned)hs[0] | ((unsigned)hs[1] << 16);
    unsigned v1 = (unsigned)hs[2] | ((unsigned)hs[3] << 16);
    if (dnxt != 0.f){ v0 = 0u; v1 = 0u; }
    unsigned* hnp = (unsigned*)&hn[cb*1024 + tid*4];
    __hip_atomic_store(hnp,     v0, __ATOMIC_RELAXED, __HIP_MEMORY_SCOPE_AGENT);
    __hip_atomic_store(hnp + 1, v1, __ATOMIC_RELAXED, __HIP_MEMORY_SCOPE_AGENT);

    // publish h_{s+1}: syncthreads drains every wave's vmcnt (sc1 stores
    // retired at the coherent point), then one RELEASE flag store by tid0.
    __syncthreads();
    if (tid == 0)
      __hip_atomic_store(&g_flags[cb], fbase + (unsigned)s + 2u, __ATOMIC_RELEASE, __HIP_MEMORY_SCOPE_AGENT);

    // off the critical path: blocked hidden store (consumed after kernel end)
    *(ushort4*)&g_hid2[(size_t)cb*((size_t)TOK*16) + (size_t)(s*BATCH + grow)*16 + gcol] = *(const ushort4*)hs;

    // prefetch next step's inputs BEFORE the next flag wait (hidden under it)
    if (s + 1 < TSTEPS){
      const float* xr = &g_xgf[(size_t)((s+1)*BATCH + grow)*4096 + col0 + gcol];
      xg0 = *(const float4*)(xr);
      xg1 = *(const float4*)(xr + 1024);
      xg2 = *(const float4*)(xr + 2048);
      xg3 = *(const float4*)(xr + 3072);
      dcur = dnxt;
      dnxt = (s + 2 < TSTEPS) ? ldsel(isf32, done_p, (s+2)*BATCH + grow) : 0.f;
    }
  }
}

// ---------------- value head: wave-per-row dot over cr slice of t3 ----------------
__global__ __launch_bounds__(256) void rowdot_kernel(const void* __restrict__ b)
{
  const unsigned short* A = g_t3 + 2048;     // cr cols of [TOK][3072]
  const unsigned short* w = g_wbuf + OCRW2;
  int row = blockIdx.x*4 + (threadIdx.x >> 6);
  int ln  = threadIdx.x & 63;
  float s = 0.f;
  for (int k = ln*8; k < HIDD; k += 512){
    bf16x8 av = *(const bf16x8*)&A[(size_t)row*3072 + k];
    bf16x8 wv = *(const bf16x8*)&w[k];
#pragma unroll
    for (int j = 0; j < 8; j++) s += b2f((unsigned short)av[j]) * b2f((unsigned short)wv[j]);
  }
  for (int o = 32; o; o >>= 1) s += __shfl_xor(s, o, 64);
  if (ln == 0) g_val[row] = s + ldmix(b, 0);
}

// ---------------- FINALIZE: only writer of d_out (fp32), full coverage ----------------
__global__ __launch_bounds__(256) void finalize(
    const int* __restrict__ action, float* __restrict__ dout)
{
  int row = blockIdx.x*4 + (threadIdx.x >> 6);
  int ln  = threadIdx.x & 63;
  size_t base = (size_t)row * NACT;
  float l0 = b2f(g_aco[base+ln])    + b2f(g_cwo[base+ln])   *b2f(g_covo[base+ln]);
  float l1 = b2f(g_aco[base+64+ln]) + b2f(g_cwo[base+64+ln])*b2f(g_covo[base+64+ln]);
  float mx = fmaxf(l0, l1);
  for (int o = 32; o; o >>= 1) mx = fmaxf(mx, __shfl_xor(mx, o, 64));
  float e0 = __expf(l0 - mx), e1 = __expf(l1 - mx);
  float sm = e0 + e1;
  for (int o = 32; o; o >>= 1) sm += __shfl_xor(sm, o, 64);
  float inv = 1.f/sm, ls = __logf(sm);
  float p0 = e0*inv, p1 = e1*inv;
  float lp0 = l0 - mx - ls, lp1 = l1 - mx - ls;
  dout[O_PROBS + base + ln]      = p0;
  dout[O_PROBS + base + 64 + ln] = p1;
  float ent = -(p0*lp0 + p1*lp1);
  for (int o = 32; o; o >>= 1) ent += __shfl_xor(ent, o, 64);
  int a = action[row];
  float lpa = (a == ln) ? lp0 : (a == ln + 64) ? lp1 : 0.f;
  for (int o = 32; o; o >>= 1) lpa += __shfl_xor(lpa, o, 64);
  if (ln == 0){
    dout[O_LOGPA + row] = lpa;
    dout[O_ENT   + row] = ent;
  }
  int gtid = blockIdx.x*256 + threadIdx.x;
  if (gtid < TOK)        dout[O_VAL + gtid] = g_val[gtid];
  if (gtid < BATCH*HIDD){
    dout[O_HT + gtid] = g_ht[gtid];
    dout[O_CT + gtid] = g_ct[gtid];
  }
}

// ---------------- host ----------------
extern "C" void kernel_launch(void* const* d_in, const int* in_sizes, int n_in,
                              void* d_out, int out_size, void* d_ws, size_t ws_size,
                              hipStream_t stream)
{
  (void)in_sizes; (void)n_in; (void)out_size; (void)d_ws; (void)ws_size;
  float* dout = (float*)d_out;

  hipLaunchKernelGGL(detect_dtype, dim3(1), dim3(256), 0, stream,
                     (const unsigned short*)d_in[0]);

  hipLaunchKernelGGL(cvt_all, dim3(512, 14), dim3(256), 0, stream,
                     d_in[0], d_in[2], d_in[6], d_in[8], d_in[10], d_in[11],
                     d_in[18], d_in[26], d_in[14], d_in[20], d_in[28],
                     d_in[22], d_in[24], d_in[16]);

  auto gemm = [&](int a_id, int lda, int ablk, int w_id, int K,
                  const void* b1, const void* b2, const void* b3, int bmode,
                  int c_id, int ldc, int N, int act, int cmode){
    hipLaunchKernelGGL(gemm_bt, dim3(N/128, TOK/128), dim3(256), 0, stream,
                       a_id, lda, ablk, w_id, K, b1, b2, b3, bmode,
                       c_id, ldc, act, cmode);
  };

  // perception MLP + hoisted input-gate GEMM
  gemm(11, OBSD, 0, 13, OBSD, d_in[7],  nullptr, nullptr, 0, 1, HIDD,   HIDD,   1, 0);
  gemm(1,  HIDD, 0, 14, HIDD, d_in[9],  nullptr, nullptr, 0, 2, HIDD,   HIDD,   1, 0);
  gemm(2,  HIDD, 0, 15, HIDD, d_in[12], d_in[13], nullptr, 0, 8, 4*HIDD, 4*HIDD, 0, 1);

  // sequential LSTM scan (persistent, 64 WGs, flag barrier + LDS-staged h)
  hipLaunchKernelGGL(lstm_scan, dim3(64), dim3(256), 0, stream,
                     d_in[1], d_in[3], d_in[4]);

  // fused head hidden GEMM: t3 = tanh(hidden @ [ac|cw|cr]w1^T + b), N=3072, blocked A
  gemm(3, 3072, 1, 17, HIDD, d_in[19], d_in[27], d_in[15], 1, 4, 3*HIDD, 3*HIDD, 1, 0);
  // output heads
  gemm(4,  3072, 0, 20, HIDD, d_in[21], nullptr, nullptr, 0, 5, NACT, NACT, 0, 0);
  gemm(9,  3072, 0, 21, HIDD, d_in[29], nullptr, nullptr, 0, 6, NACT, NACT, 0, 0);
  gemm(12, NACT, 0, 22, NACT, d_in[23], nullptr, nullptr, 0, 1, HIDD, HIDD, 1, 0);
  gemm(1,  HIDD, 0, 23, HIDD, d_in[25], nullptr, nullptr, 0, 7, NACT, NACT, 0, 0);

  // value head (staged)
  hipLaunchKernelGGL(rowdot_kernel, dim3(TOK/4), dim3(256), 0, stream, d_in[17]);

  // single final writer of d_out
  hipLaunchKernelGGL(finalize, dim3(TOK/4), dim3(256), 0, stream,
                     (const int*)d_in[5], dout);
}

// Round 2
// 2313.669 us; speedup vs baseline: 1.9425x; 1.5131x over previous
//
#include <hip/hip_runtime.h>
#include <cstdint>
#include <cstddef>

// ---------------- problem dims ----------------
#define TSTEPS 256
#define BATCH  64
#define OBSD   512
#define HIDD   1024
#define NACT   128
#define TOK    (TSTEPS*BATCH)   // 16384

// fp32 output element offsets
static constexpr size_t O_PROBS = 0;
static constexpr size_t O_LOGPA = (size_t)TOK * NACT;
static constexpr size_t O_ENT   = O_LOGPA + TOK;
static constexpr size_t O_VAL   = O_ENT + TOK;
static constexpr size_t O_HT    = O_VAL + TOK;
static constexpr size_t O_CT    = O_HT + (size_t)BATCH * HIDD;

// bf16 weight/activation pool offsets (elements)
static constexpr size_t OX     = 0;
static constexpr size_t OCOVH  = 8388608;
static constexpr size_t OSNW1  = 10485760;
static constexpr size_t OSNW2  = 11010048;
static constexpr size_t OWIH   = 12058624;
static constexpr size_t OWHH   = 16252928;
static constexpr size_t OACW1  = 20447232;   // ac|cw|cr contiguous -> one N=3072 GEMM
static constexpr size_t OCWW1  = 21495808;
static constexpr size_t OCRW1  = 22544384;
static constexpr size_t OACW2  = 23592960;
static constexpr size_t OCWW2  = 23724032;
static constexpr size_t OCOVW1 = 23855104;
static constexpr size_t OCOVW2 = 23986176;
static constexpr size_t OCRW2  = 24117248;
static constexpr size_t WBUFSZ = 24118272;

using bf16x8 = __attribute__((ext_vector_type(8))) short;
using f32x4  = __attribute__((ext_vector_type(4))) float;

// ---------------- device buffers (all resolved in device code) ----------------
__device__ __align__(16) unsigned short g_wbuf[WBUFSZ];
__device__ __align__(16) unsigned short g_hid1[(size_t)TOK*HIDD];
__device__ __align__(16) unsigned short g_hid [(size_t)TOK*HIDD];
__device__ __align__(16) float          g_xgf [(size_t)TOK*4*HIDD];
__device__ __align__(16) unsigned short g_hid2[(size_t)64*TOK*16];   // blocked hidden [cb][token][16]
__device__ __align__(16) unsigned short g_t3[(size_t)TOK*3*HIDD];    // [TOK][3072] ac|cw|cr
__device__ __align__(16) unsigned short g_aco[(size_t)TOK*NACT];
__device__ __align__(16) unsigned short g_cwo[(size_t)TOK*NACT];
__device__ __align__(16) unsigned short g_covo[(size_t)TOK*NACT];
__device__ __align__(16) unsigned short g_hp2[2*64*1024];            // blocked h ping-pong [buf][cb][row][16]
__device__ float g_val[TOK];
__device__ float g_ht[BATCH*HIDD];
__device__ float g_ct[BATCH*HIDD];
__device__ int g_isf32;
// flag-based step barrier: one monotonic epoch flag per WG.
// Values persist across launches/graph replays; g_fepoch is bumped by +512
// each launch (detect_dtype) so every launch's targets exceed all stale values.
__device__ unsigned g_flags[64];
__device__ unsigned g_fepoch;

__device__ __forceinline__ unsigned short* dev_buf(int id){
  switch(id){
    case 1:  return g_hid1;
    case 2:  return g_hid;
    case 3:  return g_hid2;
    case 4:  return g_t3;
    case 5:  return g_aco;
    case 6:  return g_cwo;
    case 7:  return g_covo;
    case 8:  return (unsigned short*)g_xgf;
    case 9:  return g_t3 + 1024;          // cw slice (row-interleaved, lda 3072)
    case 10: return g_t3 + 2048;          // cr slice
    case 11: return g_wbuf + OX;
    case 12: return g_wbuf + OCOVH;
    case 13: return g_wbuf + OSNW1;
    case 14: return g_wbuf + OSNW2;
    case 15: return g_wbuf + OWIH;
    case 16: return g_wbuf + OWHH;
    case 17: return g_wbuf + OACW1;       // 3072-row fused head weight
    case 20: return g_wbuf + OACW2;
    case 21: return g_wbuf + OCWW2;
    case 22: return g_wbuf + OCOVW1;
    case 23: return g_wbuf + OCOVW2;
    case 24: return g_wbuf + OCRW2;
    default: return nullptr;
  }
}

// ---------------- helpers ----------------
__device__ __forceinline__ float b2f(unsigned short u){
  unsigned int x = ((unsigned int)u) << 16;
  return __builtin_bit_cast(float, x);
}
__device__ __forceinline__ unsigned short f2b(float f){
  unsigned int u = __builtin_bit_cast(unsigned int, f);
  u += 0x7FFFu + ((u >> 16) & 1u);
  return (unsigned short)(u >> 16);
}
__device__ __forceinline__ float ldmix(const void* p, size_t i){
  return g_isf32 ? ((const float*)p)[i] : b2f(((const unsigned short*)p)[i]);
}
__device__ __forceinline__ float ldsel(bool f32, const void* p, size_t i){
  return f32 ? ((const float*)p)[i] : b2f(((const unsigned short*)p)[i]);
}
__device__ __forceinline__ float sigm(float x){ return 1.f/(1.f + __expf(-x)); }
__device__ __forceinline__ float tanh_f(float x){ float e = __expf(2.f*x); return 1.f - 2.f/(e + 1.f); }

// plain (L2-cached) direct-to-LDS 16B copy — used by GEMMs on read-once data
__device__ __forceinline__ void gld16(const unsigned short* g, unsigned short* l){
  __builtin_amdgcn_global_load_lds(
      (__attribute__((address_space(1))) void*)(uintptr_t)g,
      (__attribute__((address_space(3))) void*)l,
      16, 0, 0);
}
// SC1 (agent-coherent) direct-to-LDS 16B copy — bypasses the stale per-XCD L2
// and reads the coherent point (mall). CPol bit4 = SC1 on gfx940+.
__device__ __forceinline__ void gld16c(const unsigned short* g, unsigned short* l){
  __builtin_amdgcn_global_load_lds(
      (__attribute__((address_space(1))) void*)(uintptr_t)g,
      (__attribute__((address_space(3))) void*)l,
      16, 0, 16);
}

// ---------------- dtype detect (+ per-launch flag-epoch bump) ----------------
__global__ __launch_bounds__(256) void detect_dtype(const unsigned short* x){
  __shared__ int cnt;
  if (threadIdx.x == 0) cnt = 0;
  __syncthreads();
  int c = 0;
  for (int i = threadIdx.x; i < 4096; i += 256){
    float f = b2f(x[2*i]);
    if (!(fabsf(f) < 1e10f)) c++;
  }
  atomicAdd(&cnt, c);
  __syncthreads();
  if (threadIdx.x == 0){
    g_isf32 = (cnt > 64) ? 1 : 0;
    g_fepoch += 512;   // > max per-launch flag advance (TSTEPS+2), keeps epochs monotonic
  }
}

// ---------------- convert 14 arrays into g_wbuf (bf16) ----------------
__global__ __launch_bounds__(256) void cvt_all(
    const void* s0, const void* s1, const void* s2, const void* s3,
    const void* s4, const void* s5, const void* s6, const void* s7,
    const void* s8, const void* s9, const void* s10, const void* s11,
    const void* s12, const void* s13)
{
  const void* src; size_t off; int n;
  switch (blockIdx.y){
    case 0:  src=s0;  off=OX;     n=TOK*OBSD;  break;
    case 1:  src=s1;  off=OCOVH;  n=TOK*NACT;  break;
    case 2:  src=s2;  off=OSNW1;  n=HIDD*OBSD; break;
    case 3:  src=s3;  off=OSNW2;  n=HIDD*HIDD; break;
    case 4:  src=s4;  off=OWIH;   n=4*HIDD*HIDD; break;
    case 5:  src=s5;  off=OWHH;   n=4*HIDD*HIDD; break;
    case 6:  src=s6;  off=OACW1;  n=HIDD*HIDD; break;
    case 7:  src=s7;  off=OCWW1;  n=HIDD*HIDD; break;
    case 8:  src=s8;  off=OCRW1;  n=HIDD*HIDD; break;
    case 9:  src=s9;  off=OACW2;  n=NACT*HIDD; break;
    case 10: src=s10; off=OCWW2;  n=NACT*HIDD; break;
    case 11: src=s11; off=OCOVW1; n=HIDD*NACT; break;
    case 12: src=s12; off=OCOVW2; n=NACT*HIDD; break;
    default: src=s13; off=OCRW2;  n=HIDD;      break;
  }
  const bool f32 = (g_isf32 != 0);
  unsigned short* dst = g_wbuf + off;
  const int stride = gridDim.x * 256;
  for (int i = blockIdx.x*256 + threadIdx.x; i < n; i += stride){
    float v = f32 ? ((const float*)src)[i] : b2f(((const unsigned short*)src)[i]);
    dst[i] = f2b(v);
  }
}

// ---------------- tiled MFMA GEMM: C = act(A @ W^T + bias) ----------------
// ablk: A is blocked [cb][row][16] (g_hid2). bmode: 3-way bias select by col/1024.
__global__ __launch_bounds__(256) void gemm_bt(
    int a_id, int lda, int ablk, int w_id, int K,
    const void* __restrict__ b1, const void* __restrict__ b2, const void* __restrict__ b3,
    int bmode, int c_id, int ldc, int act, int cmode)
{
  __shared__ unsigned short sA[128*32];
  __shared__ unsigned short sB[128*32];
  const unsigned short* A = dev_buf(a_id);
  const unsigned short* W = dev_buf(w_id);
  void* C = dev_buf(c_id);

  const int tid  = threadIdx.x;
  const int wv   = tid >> 6, ln = tid & 63;
  const int quad = ln >> 4, l16 = ln & 15;
  const long bm = (long)blockIdx.y * 128, bn = (long)blockIdx.x * 128;
  const int wr = (wv >> 1) * 64, wc = (wv & 1) * 64;

  const f32x4 zf = {0.f, 0.f, 0.f, 0.f};
  f32x4 acc[4][4];
#pragma unroll
  for (int i = 0; i < 4; i++)
#pragma unroll
    for (int j = 0; j < 4; j++) acc[i][j] = zf;

  const int srow = wv*32 + (ln >> 2);
  const int scol = (ln & 3) * 8;
  const unsigned short* gA = A + (bm + srow)*(long)lda + scol;
  const unsigned short* gB = W + (bn + srow)*(long)K   + scol;
  unsigned short* lA = &sA[(wv*32)*32];
  unsigned short* lB = &sB[(wv*32)*32];

  for (int k0 = 0; k0 < K; k0 += 32){
    __syncthreads();
    if (ablk){
      const int kk = k0 + scol;
      const long cbase = (long)(kk >> 4) * ((long)TOK*16) + (kk & 15);
      gld16(A + cbase + (bm + srow)*16,      lA);
      gld16(A + cbase + (bm + srow + 16)*16, lA + 16*32);
    } else {
      gld16(gA + k0,                lA);
      gld16(gA + k0 + 16*(long)lda, lA + 16*32);
    }
    gld16(gB + k0,               lB);
    gld16(gB + k0 + 16*(long)K,  lB + 16*32);
    __syncthreads();
    bf16x8 af[4], bfr[4];
#pragma unroll
    for (int i = 0; i < 4; i++) af[i]  = *(const bf16x8*)&sA[(wr + 16*i + l16)*32 + quad*8];
#pragma unroll
    for (int j = 0; j < 4; j++) bfr[j] = *(const bf16x8*)&sB[(wc + 16*j + l16)*32 + quad*8];
#pragma unroll
    for (int i = 0; i < 4; i++)
#pragma unroll
      for (int j = 0; j < 4; j++)
        acc[i][j] = __builtin_amdgcn_mfma_f32_16x16x32_bf16(af[i], bfr[j], acc[i][j], 0, 0, 0);
  }

#pragma unroll
  for (int j = 0; j < 4; j++){
    const long col = bn + wc + 16*j + l16;
    float bb;
    if (bmode){
      const void* bp = (col < 1024) ? b1 : (col < 2048) ? b2 : b3;
      bb = ldmix(bp, col & 1023);
    } else {
      bb = (b1 ? ldmix(b1, col) : 0.f) + (b2 ? ldmix(b2, col) : 0.f);
    }
#pragma unroll
    for (int i = 0; i < 4; i++){
#pragma unroll
      for (int r = 0; r < 4; r++){
        const long row = bm + wr + 16*i + quad*4 + r;   // C/D: col=lane&15, row=quad*4+reg
        float v = acc[i][j][r] + bb;
        if (act) v = tanh_f(v);
        if (cmode) ((float*)C)[row*(long)ldc + col] = v;
        else ((unsigned short*)C)[row*(long)ldc + col] = f2b(v);
      }
    }
  }
}

// ---------------- persistent LSTM scan (fence-free data-flag protocol) ----------------
// 64 WGs; WG cb owns h cols [16cb,16cb+16). Wave wv owns K-quarter [256wv,256wv+256)
// and computes partial preacts for ALL 4 gates (w_hh quarter in 128 VGPRs).
// Coherence protocol (NO agent fences => no per-step buffer_wbl2/buffer_inv walks):
//   producers: h stores are sc1 write-through (vmcnt-retire == mall-visible);
//              __syncthreads() drains vmcnt; tid0 then RELAXED-stores the flag.
//   consumers: poll only their 16 producer flags (RELAXED sc1 loads), then stage
//              h via global_load_lds with SC1 cpol (bypasses stale per-XCD L2).
// Staging->MFMA interleave uses counted vmcnt (m218 template): vmcnt(28-4i)
// before MFMA iteration i hides the mall fill under the matrix pipe.
__global__ __launch_bounds__(256, 1) void lstm_scan(
    const void* __restrict__ done_p,
    const void* __restrict__ h0_p,
    const void* __restrict__ c0_p)
{
  // 128 KB: wave wv's h K-quarter lives at [wv*16384, +16384) elements.
  // After the MFMA phase consumed it, the wave's 4 partial slabs (16 KB)
  // overlay the SAME region (only this wave ever reads its h region).
  __shared__ __align__(16) unsigned short sH[65536];
  float* sPf = (float*)sH;   // slab view: wave w2 at float offset w2*8192

  const int tid  = threadIdx.x;
  const int wv   = tid >> 6, ln = tid & 63;
  const int quad = ln >> 4, l16 = ln & 15;
  const int cb   = blockIdx.x;
  const int col0 = cb * 16;
  const int grow = tid >> 2;           // gate-phase row
  const int gcol = (tid & 3) * 4;
  const bool isf32 = (g_isf32 != 0);
  const unsigned fbase = g_fepoch;     // per-launch monotonic epoch base
  const int fidx = wv*16 + (ln & 15);  // this wave's 16 producer flags

  // cell state in registers
  float cst[4];
#pragma unroll
  for (int j = 0; j < 4; j++) cst[j] = ldsel(isf32, c0_p, grow*HIDD + col0 + gcol + j);

  // h0 -> blocked ping buffer (own block), masked by done[0], sc1 write-through
  {
    float d0 = ldsel(isf32, done_p, grow);
    unsigned short t4[4];
#pragma unroll
    for (int j = 0; j < 4; j++){
      float h0 = (d0 != 0.f) ? 0.f : ldsel(isf32, h0_p, grow*HIDD + col0 + gcol + j);
      t4[j] = f2b(h0);
    }
    unsigned v0 = (unsigned)t4[0] | ((unsigned)t4[1] << 16);
    unsigned v1 = (unsigned)t4[2] | ((unsigned)t4[3] << 16);
    unsigned* hp = (unsigned*)&g_hp2[cb*1024 + tid*4];
    __hip_atomic_store(hp,     v0, __ATOMIC_RELAXED, __HIP_MEMORY_SCOPE_AGENT);
    __hip_atomic_store(hp + 1, v1, __ATOMIC_RELAXED, __HIP_MEMORY_SCOPE_AGENT);
  }

  // preload w_hh K-quarter for all 4 gates: wreg[g][i], k = wv*256 + i*32 + quad*8
  const unsigned short* wbase = g_wbuf + OWHH;
  bf16x8 wreg[4][8];
#pragma unroll
  for (int g = 0; g < 4; g++)
#pragma unroll
    for (int i = 0; i < 8; i++)
      wreg[g][i] = *(const bf16x8*)&wbase[(size_t)(g*HIDD + col0 + l16)*HIDD + wv*256 + i*32 + quad*8];

  // prefetch step-0 inputs into registers
  float4 xg0, xg1, xg2, xg3;
  {
    const float* xr = &g_xgf[(size_t)grow*4096 + col0 + gcol];
    xg0 = *(const float4*)(xr);
    xg1 = *(const float4*)(xr + 1024);
    xg2 = *(const float4*)(xr + 2048);
    xg3 = *(const float4*)(xr + 3072);
  }
  float dcur = ldsel(isf32, done_p, grow);                 // done[0]
  float dnxt = ldsel(isf32, done_p, BATCH + grow);         // done[1] (TSTEPS>1)

  // publish h0: __syncthreads drains vmcnt (sc1 stores ack'd at the mall),
  // then one RELAXED flag store — no release fence, no buffer_wbl2.
  __syncthreads();
  if (tid == 0)
    __hip_atomic_store(&g_flags[cb], fbase + 1, __ATOMIC_RELAXED, __HIP_MEMORY_SCOPE_AGENT);

  const f32x4 zf = {0.f, 0.f, 0.f, 0.f};

#define MFMA_ITER(ii, NW)                                                        \
  {                                                                              \
    asm volatile("s_waitcnt vmcnt(" #NW ")" ::: "memory");                       \
    bf16x8 af[4];                                                                \
    _Pragma("unroll")                                                            \
    for (int rt = 0; rt < 4; rt++)                                               \
      af[rt] = *(const bf16x8*)(hq + (ii)*2048 + rt*256);                        \
    _Pragma("unroll")                                                            \
    for (int rt = 0; rt < 4; rt++)                                               \
      _Pragma("unroll")                                                          \
      for (int g = 0; g < 4; g++)                                                \
        acc[g][rt] = __builtin_amdgcn_mfma_f32_16x16x32_bf16(af[rt], wreg[g][ii],\
                                                             acc[g][rt], 0, 0, 0);\
  }

  for (int s = 0; s < TSTEPS; s++){
    // per-wave wait: only this wave's 16 producers gate its K-quarter.
    // (The pre-gate __syncthreads joins all 4 waves, so the union of waits
    //  covers all 64 WGs before this WG overwrites the next-parity buffer.)
    {
      const unsigned tgt = fbase + (unsigned)s + 1u;
      unsigned f = __hip_atomic_load(&g_flags[fidx], __ATOMIC_RELAXED, __HIP_MEMORY_SCOPE_AGENT);
      while (!__all((int)(f >= tgt))){
        __builtin_amdgcn_s_sleep(1);
        f = __hip_atomic_load(&g_flags[fidx], __ATOMIC_RELAXED, __HIP_MEMORY_SCOPE_AGENT);
      }
    }

    const unsigned short* hb = g_hp2 + (s & 1)*65536;
    unsigned short*       hn = g_hp2 + ((s + 1) & 1)*65536;

    // drain stray vmem (xg prefetch, hid2 store, poll loads) so counted vmcnt
    // below is exact, then issue the wave's 32 x 1KB SC1 direct-to-LDS loads.
    asm volatile("s_waitcnt vmcnt(0)" ::: "memory");
    {
      const unsigned short* src = hb + wv*16384 + ln*8;
      unsigned short* dstb = sH + wv*16384;     // wave-uniform base; HW adds lane*16B
#pragma unroll
      for (int c2 = 0; c2 < 32; c2++)
        gld16c(src + c2*512, dstb + c2*512);
    }

    // MFMA phase interleaved with the fill: iteration i consumes loads 4i..4i+3
    const unsigned short* hq = sH + wv*16384 + (quad >> 1)*1024 + l16*16 + (quad & 1)*8;
    f32x4 acc[4][4];   // [gate][row-tile]
#pragma unroll
    for (int g = 0; g < 4; g++)
#pragma unroll
      for (int rt = 0; rt < 4; rt++) acc[g][rt] = zf;

    MFMA_ITER(0, 28)
    MFMA_ITER(1, 24)
    MFMA_ITER(2, 20)
    MFMA_ITER(3, 16)
    MFMA_ITER(4, 12)
    MFMA_ITER(5, 8)
    MFMA_ITER(6, 4)
    MFMA_ITER(7, 0)

    // write partial slabs into THIS wave's own (already-consumed) LDS region
#pragma unroll
    for (int g = 0; g < 4; g++)
#pragma unroll
      for (int rt = 0; rt < 4; rt++)
#pragma unroll
        for (int r = 0; r < 4; r++)
          sPf[wv*8192 + (g*64 + 16*rt + quad*4 + r)*20 + l16] = acc[g][rt][r];
    __syncthreads();

    // gate phase: sum 4 K-partials per gate, then LSTM cell update
    float4 pg[4];
#pragma unroll
    for (int g = 0; g < 4; g++){
      float4 p = {0.f, 0.f, 0.f, 0.f};
#pragma unroll
      for (int w2 = 0; w2 < 4; w2++){
        float4 t = *(const float4*)&sPf[w2*8192 + (g*64 + grow)*20 + gcol];
        p.x += t.x; p.y += t.y; p.z += t.z; p.w += t.w;
      }
      pg[g] = p;
    }
    const bool last = (s == TSTEPS-1);
    unsigned short hs[4];
#pragma unroll
    for (int j = 0; j < 4; j++){
      float iv = sigm (((const float*)&pg[0])[j] + ((const float*)&xg0)[j]);
      float fv = sigm (((const float*)&pg[1])[j] + ((const float*)&xg1)[j]);
      float gv = tanh_f(((const float*)&pg[2])[j] + ((const float*)&xg2)[j]);
      float ov = sigm (((const float*)&pg[3])[j] + ((const float*)&xg3)[j]);
      float cp = (dcur != 0.f) ? 0.f : cst[j];
      float c  = fv*cp + iv*gv;
      float h  = ov * tanh_f(c);
      cst[j] = c;
      hs[j] = f2b(h);
      if (last){
        g_ht[grow*HIDD + col0 + gcol + j] = h;
        g_ct[grow*HIDD + col0 + gcol + j] = c;
      }
    }
    // next-h: pre-masked by done[s+1], sc1 write-through (ack at the mall)
    unsigned v0 = (unsigned)hs[0] | ((unsigned)hs[1] << 16);
    unsigned v1 = (unsigned)hs[2] | ((unsigned)hs[3] << 16);
    if (dnxt != 0.f){ v0 = 0u; v1 = 0u; }
    unsigned* hnp = (unsigned*)&hn[cb*1024 + tid*4];
    __hip_atomic_store(hnp,     v0, __ATOMIC_RELAXED, __HIP_MEMORY_SCOPE_AGENT);
    __hip_atomic_store(hnp + 1, v1, __ATOMIC_RELAXED, __HIP_MEMORY_SCOPE_AGENT);

    // publish h_{s+1}: __syncthreads drains every wave's vmcnt (sc1 stores
    // retired at the coherent point), then one RELAXED flag store by tid0.
    __syncthreads();
    if (tid == 0)
      __hip_atomic_store(&g_flags[cb], fbase + (unsigned)s + 2u, __ATOMIC_RELAXED, __HIP_MEMORY_SCOPE_AGENT);

    // off the critical path: blocked hidden store (read by later kernels;
    // covered by the end-of-kernel system release)
    *(ushort4*)&g_hid2[(size_t)cb*((size_t)TOK*16) + (size_t)(s*BATCH + grow)*16 + gcol] = *(const ushort4*)hs;

    // prefetch next step's inputs BEFORE the next flag wait (hidden under it)
    if (s + 1 < TSTEPS){
      const float* xr = &g_xgf[(size_t)((s+1)*BATCH + grow)*4096 + col0 + gcol];
      xg0 = *(const float4*)(xr);
      xg1 = *(const float4*)(xr + 1024);
      xg2 = *(const float4*)(xr + 2048);
      xg3 = *(const float4*)(xr + 3072);
      dcur = dnxt;
      dnxt = (s + 2 < TSTEPS) ? ldsel(isf32, done_p, (s+2)*BATCH + grow) : 0.f;
    }
  }
#undef MFMA_ITER
}

// ---------------- value head: wave-per-row dot over cr slice of t3 ----------------
__global__ __launch_bounds__(256) void rowdot_kernel(const void* __restrict__ b)
{
  const unsigned short* A = g_t3 + 2048;     // cr cols of [TOK][3072]
  const unsigned short* w = g_wbuf + OCRW2;
  int row = blockIdx.x*4 + (threadIdx.x >> 6);
  int ln  = threadIdx.x & 63;
  float s = 0.f;
  for (int k = ln*8; k < HIDD; k += 512){
    bf16x8 av = *(const bf16x8*)&A[(size_t)row*3072 + k];
    bf16x8 wv = *(const bf16x8*)&w[k];
#pragma unroll
    for (int j = 0; j < 8; j++) s += b2f((unsigned short)av[j]) * b2f((unsigned short)wv[j]);
  }
  for (int o = 32; o; o >>= 1) s += __shfl_xor(s, o, 64);
  if (ln == 0) g_val[row] = s + ldmix(b, 0);
}

// ---------------- FINALIZE: only writer of d_out (fp32), full coverage ----------------
__global__ __launch_bounds__(256) void finalize(
    const int* __restrict__ action, float* __restrict__ dout)
{
  int row = blockIdx.x*4 + (threadIdx.x >> 6);
  int ln  = threadIdx.x & 63;
  size_t base = (size_t)row * NACT;
  float l0 = b2f(g_aco[base+ln])    + b2f(g_cwo[base+ln])   *b2f(g_covo[base+ln]);
  float l1 = b2f(g_aco[base+64+ln]) + b2f(g_cwo[base+64+ln])*b2f(g_covo[base+64+ln]);
  float mx = fmaxf(l0, l1);
  for (int o = 32; o; o >>= 1) mx = fmaxf(mx, __shfl_xor(mx, o, 64));
  float e0 = __expf(l0 - mx), e1 = __expf(l1 - mx);
  float sm = e0 + e1;
  for (int o = 32; o; o >>= 1) sm += __shfl_xor(sm, o, 64);
  float inv = 1.f/sm, ls = __logf(sm);
  float p0 = e0*inv, p1 = e1*inv;
  float lp0 = l0 - mx - ls, lp1 = l1 - mx - ls;
  dout[O_PROBS + base + ln]      = p0;
  dout[O_PROBS + base + 64 + ln] = p1;
  float ent = -(p0*lp0 + p1*lp1);
  for (int o = 32; o; o >>= 1) ent += __shfl_xor(ent, o, 64);
  int a = action[row];
  float lpa = (a == ln) ? lp0 : (a == ln + 64) ? lp1 : 0.f;
  for (int o = 32; o; o >>= 1) lpa += __shfl_xor(lpa, o, 64);
  if (ln == 0){
    dout[O_LOGPA + row] = lpa;
    dout[O_ENT   + row] = ent;
  }
  int gtid = blockIdx.x*256 + threadIdx.x;
  if (gtid < TOK)        dout[O_VAL + gtid] = g_val[gtid];
  if (gtid < BATCH*HIDD){
    dout[O_HT + gtid] = g_ht[gtid];
    dout[O_CT + gtid] = g_ct[gtid];
  }
}

// ---------------- host ----------------
extern "C" void kernel_launch(void* const* d_in, const int* in_sizes, int n_in,
                              void* d_out, int out_size, void* d_ws, size_t ws_size,
                              hipStream_t stream)
{
  (void)in_sizes; (void)n_in; (void)out_size; (void)d_ws; (void)ws_size;
  float* dout = (float*)d_out;

  hipLaunchKernelGGL(detect_dtype, dim3(1), dim3(256), 0, stream,
                     (const unsigned short*)d_in[0]);

  hipLaunchKernelGGL(cvt_all, dim3(512, 14), dim3(256), 0, stream,
                     d_in[0], d_in[2], d_in[6], d_in[8], d_in[10], d_in[11],
                     d_in[18], d_in[26], d_in[14], d_in[20], d_in[28],
                     d_in[22], d_in[24], d_in[16]);

  auto gemm = [&](int a_id, int lda, int ablk, int w_id, int K,
                  const void* b1, const void* b2, const void* b3, int bmode,
                  int c_id, int ldc, int N, int act, int cmode){
    hipLaunchKernelGGL(gemm_bt, dim3(N/128, TOK/128), dim3(256), 0, stream,
                       a_id, lda, ablk, w_id, K, b1, b2, b3, bmode,
                       c_id, ldc, act, cmode);
  };

  // perception MLP + hoisted input-gate GEMM
  gemm(11, OBSD, 0, 13, OBSD, d_in[7],  nullptr, nullptr, 0, 1, HIDD,   HIDD,   1, 0);
  gemm(1,  HIDD, 0, 14, HIDD, d_in[9],  nullptr, nullptr, 0, 2, HIDD,   HIDD,   1, 0);
  gemm(2,  HIDD, 0, 15, HIDD, d_in[12], d_in[13], nullptr, 0, 8, 4*HIDD, 4*HIDD, 0, 1);

  // sequential LSTM scan (persistent, 64 WGs, fence-free flag protocol)
  hipLaunchKernelGGL(lstm_scan, dim3(64), dim3(256), 0, stream,
                     d_in[1], d_in[3], d_in[4]);

  // fused head hidden GEMM: t3 = tanh(hidden @ [ac|cw|cr]w1^T + b), N=3072, blocked A
  gemm(3, 3072, 1, 17, HIDD, d_in[19], d_in[27], d_in[15], 1, 4, 3*HIDD, 3*HIDD, 1, 0);
  // output heads
  gemm(4,  3072, 0, 20, HIDD, d_in[21], nullptr, nullptr, 0, 5, NACT, NACT, 0, 0);
  gemm(9,  3072, 0, 21, HIDD, d_in[29], nullptr, nullptr, 0, 6, NACT, NACT, 0, 0);
  gemm(12, NACT, 0, 22, NACT, d_in[23], nullptr, nullptr, 0, 1, HIDD, HIDD, 1, 0);
  gemm(1,  HIDD, 0, 23, HIDD, d_in[25], nullptr, nullptr, 0, 7, NACT, NACT, 0, 0);

  // value head (staged)
  hipLaunchKernelGGL(rowdot_kernel, dim3(TOK/4), dim3(256), 0, stream, d_in[17]);

  // single final writer of d_out
  hipLaunchKernelGGL(finalize, dim3(TOK/4), dim3(256), 0, stream,
                     (const int*)d_in[5], dout);
}

// Round 3
// 1564.932 us; speedup vs baseline: 2.8719x; 1.4784x over previous
//
#include <hip/hip_runtime.h>
#include <cstdint>
#include <cstddef>

// ---------------- problem dims ----------------
#define TSTEPS 256
#define BATCH  64
#define OBSD   512
#define HIDD   1024
#define NACT   128
#define TOK    (TSTEPS*BATCH)   // 16384

// fp32 output element offsets
static constexpr size_t O_PROBS = 0;
static constexpr size_t O_LOGPA = (size_t)TOK * NACT;
static constexpr size_t O_ENT   = O_LOGPA + TOK;
static constexpr size_t O_VAL   = O_ENT + TOK;
static constexpr size_t O_HT    = O_VAL + TOK;
static constexpr size_t O_CT    = O_HT + (size_t)BATCH * HIDD;

// bf16 weight/activation pool offsets (elements)
static constexpr size_t OX     = 0;
static constexpr size_t OCOVH  = 8388608;
static constexpr size_t OSNW1  = 10485760;
static constexpr size_t OSNW2  = 11010048;
static constexpr size_t OWIH   = 12058624;
static constexpr size_t OWHH   = 16252928;
static constexpr size_t OACW1  = 20447232;   // ac|cw|cr contiguous -> one N=3072 GEMM
static constexpr size_t OCWW1  = 21495808;
static constexpr size_t OCRW1  = 22544384;
static constexpr size_t OACW2  = 23592960;
static constexpr size_t OCWW2  = 23724032;
static constexpr size_t OCOVW1 = 23855104;
static constexpr size_t OCOVW2 = 23986176;
static constexpr size_t OCRW2  = 24117248;
static constexpr size_t WBUFSZ = 24118272;

using bf16x8 = __attribute__((ext_vector_type(8))) short;
using f32x4  = __attribute__((ext_vector_type(4))) float;

// ---------------- device buffers (all resolved in device code) ----------------
__device__ __align__(16) unsigned short g_wbuf[WBUFSZ];
__device__ __align__(16) unsigned short g_hid1[(size_t)TOK*HIDD];
__device__ __align__(16) unsigned short g_hid [(size_t)TOK*HIDD];
__device__ __align__(16) float          g_xgf [(size_t)TOK*4*HIDD];
__device__ __align__(16) unsigned short g_hid2[(size_t)64*TOK*16];   // blocked hidden [cb][token][16]
__device__ __align__(16) unsigned short g_t3[(size_t)TOK*3*HIDD];    // [TOK][3072] ac|cw|cr
__device__ __align__(16) unsigned short g_aco[(size_t)TOK*NACT];
__device__ __align__(16) unsigned short g_cwo[(size_t)TOK*NACT];
__device__ __align__(16) unsigned short g_covo[(size_t)TOK*NACT];
// blocked h ping-pong: [parity][group(4)][shard(64)][row(16)][col(16)] bf16
__device__ __align__(16) unsigned short g_hp2[2*64*1024];
__device__ float g_val[TOK];
__device__ float g_ht[BATCH*HIDD];
__device__ float g_ct[BATCH*HIDD];
__device__ int g_isf32;
// flag-based step barrier: one monotonic epoch flag per WG (256 WGs).
// Values persist across launches/graph replays; g_fepoch is bumped by +512
// each launch (detect_dtype) so every launch's targets exceed all stale values.
__device__ unsigned g_flags[256];
__device__ unsigned g_fepoch;

__device__ __forceinline__ unsigned short* dev_buf(int id){
  switch(id){
    case 1:  return g_hid1;
    case 2:  return g_hid;
    case 3:  return g_hid2;
    case 4:  return g_t3;
    case 5:  return g_aco;
    case 6:  return g_cwo;
    case 7:  return g_covo;
    case 8:  return (unsigned short*)g_xgf;
    case 9:  return g_t3 + 1024;          // cw slice (row-interleaved, lda 3072)
    case 10: return g_t3 + 2048;          // cr slice
    case 11: return g_wbuf + OX;
    case 12: return g_wbuf + OCOVH;
    case 13: return g_wbuf + OSNW1;
    case 14: return g_wbuf + OSNW2;
    case 15: return g_wbuf + OWIH;
    case 16: return g_wbuf + OWHH;
    case 17: return g_wbuf + OACW1;       // 3072-row fused head weight
    case 20: return g_wbuf + OACW2;
    case 21: return g_wbuf + OCWW2;
    case 22: return g_wbuf + OCOVW1;
    case 23: return g_wbuf + OCOVW2;
    case 24: return g_wbuf + OCRW2;
    default: return nullptr;
  }
}

// ---------------- helpers ----------------
__device__ __forceinline__ float b2f(unsigned short u){
  unsigned int x = ((unsigned int)u) << 16;
  return __builtin_bit_cast(float, x);
}
__device__ __forceinline__ unsigned short f2b(float f){
  unsigned int u = __builtin_bit_cast(unsigned int, f);
  u += 0x7FFFu + ((u >> 16) & 1u);
  return (unsigned short)(u >> 16);
}
__device__ __forceinline__ float ldmix(const void* p, size_t i){
  return g_isf32 ? ((const float*)p)[i] : b2f(((const unsigned short*)p)[i]);
}
__device__ __forceinline__ float ldsel(bool f32, const void* p, size_t i){
  return f32 ? ((const float*)p)[i] : b2f(((const unsigned short*)p)[i]);
}
__device__ __forceinline__ float sigm(float x){ return 1.f/(1.f + __expf(-x)); }
__device__ __forceinline__ float tanh_f(float x){ float e = __expf(2.f*x); return 1.f - 2.f/(e + 1.f); }

// plain (L2-cached) direct-to-LDS 16B copy — used by GEMMs on read-once data
__device__ __forceinline__ void gld16(const unsigned short* g, unsigned short* l){
  __builtin_amdgcn_global_load_lds(
      (__attribute__((address_space(1))) void*)(uintptr_t)g,
      (__attribute__((address_space(3))) void*)l,
      16, 0, 0);
}
// SC1 (agent-coherent) direct-to-LDS 16B copy — bypasses the stale per-XCD L2
// and reads the coherent point (mall). CPol bit4 = SC1 on gfx940+.
__device__ __forceinline__ void gld16c(const unsigned short* g, unsigned short* l){
  __builtin_amdgcn_global_load_lds(
      (__attribute__((address_space(1))) void*)(uintptr_t)g,
      (__attribute__((address_space(3))) void*)l,
      16, 0, 16);
}

// ---------------- dtype detect (+ per-launch flag-epoch bump) ----------------
__global__ __launch_bounds__(256) void detect_dtype(const unsigned short* x){
  __shared__ int cnt;
  if (threadIdx.x == 0) cnt = 0;
  __syncthreads();
  int c = 0;
  for (int i = threadIdx.x; i < 4096; i += 256){
    float f = b2f(x[2*i]);
    if (!(fabsf(f) < 1e10f)) c++;
  }
  atomicAdd(&cnt, c);
  __syncthreads();
  if (threadIdx.x == 0){
    g_isf32 = (cnt > 64) ? 1 : 0;
    g_fepoch += 512;   // > max per-launch flag advance (TSTEPS+2), keeps epochs monotonic
  }
}

// ---------------- convert 14 arrays into g_wbuf (bf16) ----------------
__global__ __launch_bounds__(256) void cvt_all(
    const void* s0, const void* s1, const void* s2, const void* s3,
    const void* s4, const void* s5, const void* s6, const void* s7,
    const void* s8, const void* s9, const void* s10, const void* s11,
    const void* s12, const void* s13)
{
  const void* src; size_t off; int n;
  switch (blockIdx.y){
    case 0:  src=s0;  off=OX;     n=TOK*OBSD;  break;
    case 1:  src=s1;  off=OCOVH;  n=TOK*NACT;  break;
    case 2:  src=s2;  off=OSNW1;  n=HIDD*OBSD; break;
    case 3:  src=s3;  off=OSNW2;  n=HIDD*HIDD; break;
    case 4:  src=s4;  off=OWIH;   n=4*HIDD*HIDD; break;
    case 5:  src=s5;  off=OWHH;   n=4*HIDD*HIDD; break;
    case 6:  src=s6;  off=OACW1;  n=HIDD*HIDD; break;
    case 7:  src=s7;  off=OCWW1;  n=HIDD*HIDD; break;
    case 8:  src=s8;  off=OCRW1;  n=HIDD*HIDD; break;
    case 9:  src=s9;  off=OACW2;  n=NACT*HIDD; break;
    case 10: src=s10; off=OCWW2;  n=NACT*HIDD; break;
    case 11: src=s11; off=OCOVW1; n=HIDD*NACT; break;
    case 12: src=s12; off=OCOVW2; n=NACT*HIDD; break;
    default: src=s13; off=OCRW2;  n=HIDD;      break;
  }
  const bool f32 = (g_isf32 != 0);
  unsigned short* dst = g_wbuf + off;
  const int stride = gridDim.x * 256;
  for (int i = blockIdx.x*256 + threadIdx.x; i < n; i += stride){
    float v = f32 ? ((const float*)src)[i] : b2f(((const unsigned short*)src)[i]);
    dst[i] = f2b(v);
  }
}

// ---------------- tiled MFMA GEMM: C = act(A @ W^T + bias) ----------------
// ablk: A is blocked [cb][row][16] (g_hid2). bmode: 3-way bias select by col/1024.
__global__ __launch_bounds__(256) void gemm_bt(
    int a_id, int lda, int ablk, int w_id, int K,
    const void* __restrict__ b1, const void* __restrict__ b2, const void* __restrict__ b3,
    int bmode, int c_id, int ldc, int act, int cmode)
{
  __shared__ unsigned short sA[128*32];
  __shared__ unsigned short sB[128*32];
  const unsigned short* A = dev_buf(a_id);
  const unsigned short* W = dev_buf(w_id);
  void* C = dev_buf(c_id);

  const int tid  = threadIdx.x;
  const int wv   = tid >> 6, ln = tid & 63;
  const int quad = ln >> 4, l16 = ln & 15;
  const long bm = (long)blockIdx.y * 128, bn = (long)blockIdx.x * 128;
  const int wr = (wv >> 1) * 64, wc = (wv & 1) * 64;

  const f32x4 zf = {0.f, 0.f, 0.f, 0.f};
  f32x4 acc[4][4];
#pragma unroll
  for (int i = 0; i < 4; i++)
#pragma unroll
    for (int j = 0; j < 4; j++) acc[i][j] = zf;

  const int srow = wv*32 + (ln >> 2);
  const int scol = (ln & 3) * 8;
  const unsigned short* gA = A + (bm + srow)*(long)lda + scol;
  const unsigned short* gB = W + (bn + srow)*(long)K   + scol;
  unsigned short* lA = &sA[(wv*32)*32];
  unsigned short* lB = &sB[(wv*32)*32];

  for (int k0 = 0; k0 < K; k0 += 32){
    __syncthreads();
    if (ablk){
      const int kk = k0 + scol;
      const long cbase = (long)(kk >> 4) * ((long)TOK*16) + (kk & 15);
      gld16(A + cbase + (bm + srow)*16,      lA);
      gld16(A + cbase + (bm + srow + 16)*16, lA + 16*32);
    } else {
      gld16(gA + k0,                lA);
      gld16(gA + k0 + 16*(long)lda, lA + 16*32);
    }
    gld16(gB + k0,               lB);
    gld16(gB + k0 + 16*(long)K,  lB + 16*32);
    __syncthreads();
    bf16x8 af[4], bfr[4];
#pragma unroll
    for (int i = 0; i < 4; i++) af[i]  = *(const bf16x8*)&sA[(wr + 16*i + l16)*32 + quad*8];
#pragma unroll
    for (int j = 0; j < 4; j++) bfr[j] = *(const bf16x8*)&sB[(wc + 16*j + l16)*32 + quad*8];
#pragma unroll
    for (int i = 0; i < 4; i++)
#pragma unroll
      for (int j = 0; j < 4; j++)
        acc[i][j] = __builtin_amdgcn_mfma_f32_16x16x32_bf16(af[i], bfr[j], acc[i][j], 0, 0, 0);
  }

#pragma unroll
  for (int j = 0; j < 4; j++){
    const long col = bn + wc + 16*j + l16;
    float bb;
    if (bmode){
      const void* bp = (col < 1024) ? b1 : (col < 2048) ? b2 : b3;
      bb = ldmix(bp, col & 1023);
    } else {
      bb = (b1 ? ldmix(b1, col) : 0.f) + (b2 ? ldmix(b2, col) : 0.f);
    }
#pragma unroll
    for (int i = 0; i < 4; i++){
#pragma unroll
      for (int r = 0; r < 4; r++){
        const long row = bm + wr + 16*i + quad*4 + r;   // C/D: col=lane&15, row=quad*4+reg
        float v = acc[i][j][r] + bb;
        if (act) v = tanh_f(v);
        if (cmode) ((float*)C)[row*(long)ldc + col] = v;
        else ((unsigned short*)C)[row*(long)ldc + col] = f2b(v);
      }
    }
  }
}

// ---------------- persistent LSTM scan: 4 independent batch-groups x 64 shards ------
// The LSTM recurrence is batch-independent, so the 64 batch rows split into 4
// groups of 16; each group runs its own 64-WG column exchange (disjoint flags
// and h regions). WG (grp, shrd) computes rows [16grp,+16) x cols [16shrd,+16).
// Wave wv owns K-quarter [256wv,+256) (= 16 producer shards) and computes
// partial preacts for all 4 gates (w_hh quarter in 128 VGPRs).
// Fence-free coherence (proven R2): producers store h sc1 write-through
// (vmcnt-retire == mall-visible), __syncthreads drains, tid0 RELAXED-stores
// the flag; consumers poll their 16 producer flags (RELAXED sc1), then stage
// h via SC1 global_load_lds (bypasses stale per-XCD L2).
// Per-step staging is 32 KB/WG (8 KB/wave = 8 loads), interleaved with MFMA
// via exact counted vmcnt(7-i). xg prefetch is drained BEFORE the poll so its
// HBM latency overlaps the producer wait, never follows it.
__global__ __launch_bounds__(256, 1) void lstm_scan(
    const void* __restrict__ done_p,
    const void* __restrict__ h0_p,
    const void* __restrict__ c0_p)
{
  // 32 KB: wave wv's staged h K-quarter (8 KB) at ushort offset wv*4096.
  // After the MFMA phase consumed it, the wave's 4 gate-partial slabs (5 KB)
  // overlay the same region (only this wave ever reads its staged region).
  __shared__ __align__(16) unsigned short sH[16384];
  float* sPf = (float*)sH;     // slab view: wave w2 at float offset w2*2048

  const int tid  = threadIdx.x;
  const int wv   = tid >> 6, ln = tid & 63;
  const int quad = ln >> 4, l16 = ln & 15;
  const int cbid = blockIdx.x;
  const int grp  = cbid >> 6;          // batch-group: rows [grp*16, +16)
  const int shrd = cbid & 63;          // col-shard:  cols [shrd*16, +16)
  const int rr0  = grp * 16;
  const int cc0  = shrd * 16;
  const int row  = tid >> 4;           // gate-phase batch row (0..15)
  const int col  = tid & 15;           // gate-phase col (0..15)
  const bool isf32 = (g_isf32 != 0);
  const unsigned fbase = g_fepoch;     // per-launch monotonic epoch base
  const int fidx = grp*64 + wv*16 + (ln & 15);   // this wave's 16 producer flags

  // cell state: one element per thread
  float cst = ldsel(isf32, c0_p, (size_t)(rr0 + row)*HIDD + cc0 + col);

  // h0 -> parity-0 slot (own tile), masked by done[0], packed pairs, sc1
  {
    float d0 = ldsel(isf32, done_p, rr0 + row);
    float h0 = (d0 != 0.f) ? 0.f : ldsel(isf32, h0_p, (size_t)(rr0 + row)*HIDD + cc0 + col);
    unsigned short hu = f2b(h0);
    unsigned hv = (unsigned)hu | ((unsigned)(unsigned short)__shfl_down((int)hu, 1, 64) << 16);
    if ((ln & 1) == 0){
      unsigned* hp = (unsigned*)&g_hp2[grp*16384 + shrd*256 + row*16 + col];
      __hip_atomic_store(hp, hv, __ATOMIC_RELAXED, __HIP_MEMORY_SCOPE_AGENT);
    }
  }

  // preload w_hh K-quarter for all 4 gates: wreg[g][i], k = wv*256 + i*32 + quad*8
  const unsigned short* wbase = g_wbuf + OWHH;
  bf16x8 wreg[4][8];
#pragma unroll
  for (int g = 0; g < 4; g++)
#pragma unroll
    for (int i = 0; i < 8; i++)
      wreg[g][i] = *(const bf16x8*)&wbase[(size_t)(g*HIDD + cc0 + l16)*HIDD + wv*256 + i*32 + quad*8];

  // prefetch step-0 inputs into registers (4 gate-preacts per thread)
  float xgv0, xgv1, xgv2, xgv3;
  {
    const float* xr = &g_xgf[(size_t)(rr0 + row)*4096 + cc0 + col];
    xgv0 = xr[0]; xgv1 = xr[1024]; xgv2 = xr[2048]; xgv3 = xr[3072];
  }
  float dcur = ldsel(isf32, done_p, rr0 + row);             // done[0]
  float dnxt = ldsel(isf32, done_p, BATCH + rr0 + row);     // done[1]

  // publish h0: __syncthreads drains vmcnt (sc1 stores ack'd at the mall),
  // then one RELAXED flag store — no release fence, no buffer_wbl2.
  __syncthreads();
  if (tid == 0)
    __hip_atomic_store(&g_flags[cbid], fbase + 1, __ATOMIC_RELAXED, __HIP_MEMORY_SCOPE_AGENT);

  const f32x4 zf = {0.f, 0.f, 0.f, 0.f};

#define MFMA_ITER(ii, NW)                                                        \
  {                                                                              \
    asm volatile("s_waitcnt vmcnt(" #NW ")" ::: "memory");                       \
    bf16x8 af = *(const bf16x8*)(hq + (ii)*512);                                 \
    _Pragma("unroll")                                                            \
    for (int g = 0; g < 4; g++)                                                  \
      acc[g] = __builtin_amdgcn_mfma_f32_16x16x32_bf16(af, wreg[g][ii],          \
                                                       acc[g], 0, 0, 0);         \
  }

  for (int s = 0; s < TSTEPS; s++){
    // drain ALL prior vmem (xg prefetch, h/hid2 stores) BEFORE the poll:
    // their latency overlaps the producer wait, and the staged-load vmcnt
    // counting below stays exact.
    asm volatile("s_waitcnt vmcnt(0)" ::: "memory");

    // per-wave wait on this wave's 16 producer shards (within our group).
    // Union over the 4 waves = all 64 group shards; the post-gate
    // __syncthreads joins the waves, preserving the overwrite-safety proof.
    {
      const unsigned tgt = fbase + (unsigned)s + 1u;
      unsigned f = __hip_atomic_load(&g_flags[fidx], __ATOMIC_RELAXED, __HIP_MEMORY_SCOPE_AGENT);
      while (!__all((int)(f >= tgt))){
        __builtin_amdgcn_s_sleep(1);
        f = __hip_atomic_load(&g_flags[fidx], __ATOMIC_RELAXED, __HIP_MEMORY_SCOPE_AGENT);
      }
    }
    asm volatile("s_waitcnt vmcnt(0)" ::: "memory");   // poll loads drained

    const unsigned short* hb = g_hp2 + (s & 1)*65536 + grp*16384;
    unsigned short*       hn = g_hp2 + ((s + 1) & 1)*65536 + grp*16384;

    // stage this wave's 8 KB h K-quarter (16 shards x 512B) into LDS:
    // 8 x 1KB SC1 direct-to-LDS loads, zero VGPR cost.
    {
      const unsigned short* src = hb + wv*4096 + ln*8;
      unsigned short* dstb = sH + wv*4096;     // wave-uniform base; HW adds lane*16B
#pragma unroll
      for (int c2 = 0; c2 < 8; c2++)
        gld16c(src + c2*512, dstb + c2*512);
    }

    // MFMA phase interleaved with the fill: iteration i consumes load i.
    const unsigned short* hq = sH + wv*4096 + (quad >> 1)*256 + l16*16 + (quad & 1)*8;
    f32x4 acc[4];   // [gate]
#pragma unroll
    for (int g = 0; g < 4; g++) acc[g] = zf;

    MFMA_ITER(0, 7)
    MFMA_ITER(1, 6)
    MFMA_ITER(2, 5)
    MFMA_ITER(3, 4)
    MFMA_ITER(4, 3)
    MFMA_ITER(5, 2)
    MFMA_ITER(6, 1)
    MFMA_ITER(7, 0)

    // write gate-partial slabs into THIS wave's own (consumed) LDS region
#pragma unroll
    for (int g = 0; g < 4; g++)
#pragma unroll
      for (int r = 0; r < 4; r++)
        sPf[wv*2048 + g*320 + (quad*4 + r)*20 + l16] = acc[g][r];
    __syncthreads();

    // gate phase: sum 4 K-partials per gate, then LSTM cell update (1 elem/thread)
    float pg0 = 0.f, pg1 = 0.f, pg2 = 0.f, pg3 = 0.f;
#pragma unroll
    for (int w2 = 0; w2 < 4; w2++){
      const float* sb = &sPf[w2*2048 + row*20 + col];
      pg0 += sb[0];
      pg1 += sb[320];
      pg2 += sb[640];
      pg3 += sb[960];
    }
    const bool last = (s == TSTEPS-1);
    float iv = sigm (pg0 + xgv0);
    float fv = sigm (pg1 + xgv1);
    float gv = tanh_f(pg2 + xgv2);
    float ov = sigm (pg3 + xgv3);
    float cp = (dcur != 0.f) ? 0.f : cst;
    float c  = fv*cp + iv*gv;
    float h  = ov * tanh_f(c);
    cst = c;
    if (last){
      g_ht[(rr0 + row)*HIDD + cc0 + col] = h;
      g_ct[(rr0 + row)*HIDD + cc0 + col] = c;
    }
    // pack col-pairs and store next-h (pre-masked by done[s+1], sc1)
    unsigned short hu = f2b(h);
    unsigned hv = (unsigned)hu | ((unsigned)(unsigned short)__shfl_down((int)hu, 1, 64) << 16);
    unsigned hm = (dnxt != 0.f) ? 0u : hv;
    if ((ln & 1) == 0){
      unsigned* hnp = (unsigned*)&hn[shrd*256 + row*16 + col];
      __hip_atomic_store(hnp, hm, __ATOMIC_RELAXED, __HIP_MEMORY_SCOPE_AGENT);
    }

    // publish h_{s+1}: __syncthreads drains every wave's vmcnt (sc1 stores
    // retired at the coherent point), then one RELAXED flag store by tid0.
    __syncthreads();
    if (tid == 0)
      __hip_atomic_store(&g_flags[cbid], fbase + (unsigned)s + 2u, __ATOMIC_RELAXED, __HIP_MEMORY_SCOPE_AGENT);

    // off the critical path: blocked hidden store (read by later kernels)
    const int token = s*BATCH + rr0 + row;
    if ((ln & 1) == 0)
      *(unsigned*)&g_hid2[(size_t)shrd*((size_t)TOK*16) + (size_t)token*16 + col] = hv;

    // prefetch next step's inputs BEFORE the next poll (hidden under it)
    if (s + 1 < TSTEPS){
      const float* xr = &g_xgf[(size_t)((s+1)*BATCH + rr0 + row)*4096 + cc0 + col];
      xgv0 = xr[0]; xgv1 = xr[1024]; xgv2 = xr[2048]; xgv3 = xr[3072];
      dcur = dnxt;
      dnxt = (s + 2 < TSTEPS) ? ldsel(isf32, done_p, (size_t)(s+2)*BATCH + rr0 + row) : 0.f;
    }
  }
#undef MFMA_ITER
}

// ---------------- value head: wave-per-row dot over cr slice of t3 ----------------
__global__ __launch_bounds__(256) void rowdot_kernel(const void* __restrict__ b)
{
  const unsigned short* A = g_t3 + 2048;     // cr cols of [TOK][3072]
  const unsigned short* w = g_wbuf + OCRW2;
  int row = blockIdx.x*4 + (threadIdx.x >> 6);
  int ln  = threadIdx.x & 63;
  float s = 0.f;
  for (int k = ln*8; k < HIDD; k += 512){
    bf16x8 av = *(const bf16x8*)&A[(size_t)row*3072 + k];
    bf16x8 wv = *(const bf16x8*)&w[k];
#pragma unroll
    for (int j = 0; j < 8; j++) s += b2f((unsigned short)av[j]) * b2f((unsigned short)wv[j]);
  }
  for (int o = 32; o; o >>= 1) s += __shfl_xor(s, o, 64);
  if (ln == 0) g_val[row] = s + ldmix(b, 0);
}

// ---------------- FINALIZE: only writer of d_out (fp32), full coverage ----------------
__global__ __launch_bounds__(256) void finalize(
    const int* __restrict__ action, float* __restrict__ dout)
{
  int row = blockIdx.x*4 + (threadIdx.x >> 6);
  int ln  = threadIdx.x & 63;
  size_t base = (size_t)row * NACT;
  float l0 = b2f(g_aco[base+ln])    + b2f(g_cwo[base+ln])   *b2f(g_covo[base+ln]);
  float l1 = b2f(g_aco[base+64+ln]) + b2f(g_cwo[base+64+ln])*b2f(g_covo[base+64+ln]);
  float mx = fmaxf(l0, l1);
  for (int o = 32; o; o >>= 1) mx = fmaxf(mx, __shfl_xor(mx, o, 64));
  float e0 = __expf(l0 - mx), e1 = __expf(l1 - mx);
  float sm = e0 + e1;
  for (int o = 32; o; o >>= 1) sm += __shfl_xor(sm, o, 64);
  float inv = 1.f/sm, ls = __logf(sm);
  float p0 = e0*inv, p1 = e1*inv;
  float lp0 = l0 - mx - ls, lp1 = l1 - mx - ls;
  dout[O_PROBS + base + ln]      = p0;
  dout[O_PROBS + base + 64 + ln] = p1;
  float ent = -(p0*lp0 + p1*lp1);
  for (int o = 32; o; o >>= 1) ent += __shfl_xor(ent, o, 64);
  int a = action[row];
  float lpa = (a == ln) ? lp0 : (a == ln + 64) ? lp1 : 0.f;
  for (int o = 32; o; o >>= 1) lpa += __shfl_xor(lpa, o, 64);
  if (ln == 0){
    dout[O_LOGPA + row] = lpa;
    dout[O_ENT   + row] = ent;
  }
  int gtid = blockIdx.x*256 + threadIdx.x;
  if (gtid < TOK)        dout[O_VAL + gtid] = g_val[gtid];
  if (gtid < BATCH*HIDD){
    dout[O_HT + gtid] = g_ht[gtid];
    dout[O_CT + gtid] = g_ct[gtid];
  }
}

// ---------------- host ----------------
extern "C" void kernel_launch(void* const* d_in, const int* in_sizes, int n_in,
                              void* d_out, int out_size, void* d_ws, size_t ws_size,
                              hipStream_t stream)
{
  (void)in_sizes; (void)n_in; (void)out_size; (void)d_ws; (void)ws_size;
  float* dout = (float*)d_out;

  hipLaunchKernelGGL(detect_dtype, dim3(1), dim3(256), 0, stream,
                     (const unsigned short*)d_in[0]);

  hipLaunchKernelGGL(cvt_all, dim3(512, 14), dim3(256), 0, stream,
                     d_in[0], d_in[2], d_in[6], d_in[8], d_in[10], d_in[11],
                     d_in[18], d_in[26], d_in[14], d_in[20], d_in[28],
                     d_in[22], d_in[24], d_in[16]);

  auto gemm = [&](int a_id, int lda, int ablk, int w_id, int K,
                  const void* b1, const void* b2, const void* b3, int bmode,
                  int c_id, int ldc, int N, int act, int cmode){
    hipLaunchKernelGGL(gemm_bt, dim3(N/128, TOK/128), dim3(256), 0, stream,
                       a_id, lda, ablk, w_id, K, b1, b2, b3, bmode,
                       c_id, ldc, act, cmode);
  };

  // perception MLP + hoisted input-gate GEMM
  gemm(11, OBSD, 0, 13, OBSD, d_in[7],  nullptr, nullptr, 0, 1, HIDD,   HIDD,   1, 0);
  gemm(1,  HIDD, 0, 14, HIDD, d_in[9],  nullptr, nullptr, 0, 2, HIDD,   HIDD,   1, 0);
  gemm(2,  HIDD, 0, 15, HIDD, d_in[12], d_in[13], nullptr, 0, 8, 4*HIDD, 4*HIDD, 0, 1);

  // sequential LSTM scan: 256 persistent WGs = 4 batch-groups x 64 shards
  hipLaunchKernelGGL(lstm_scan, dim3(256), dim3(256), 0, stream,
                     d_in[1], d_in[3], d_in[4]);

  // fused head hidden GEMM: t3 = tanh(hidden @ [ac|cw|cr]w1^T + b), N=3072, blocked A
  gemm(3, 3072, 1, 17, HIDD, d_in[19], d_in[27], d_in[15], 1, 4, 3*HIDD, 3*HIDD, 1, 0);
  // output heads
  gemm(4,  3072, 0, 20, HIDD, d_in[21], nullptr, nullptr, 0, 5, NACT, NACT, 0, 0);
  gemm(9,  3072, 0, 21, HIDD, d_in[29], nullptr, nullptr, 0, 6, NACT, NACT, 0, 0);
  gemm(12, NACT, 0, 22, NACT, d_in[23], nullptr, nullptr, 0, 1, HIDD, HIDD, 1, 0);
  gemm(1,  HIDD, 0, 23, HIDD, d_in[25], nullptr, nullptr, 0, 7, NACT, NACT, 0, 0);

  // value head (staged)
  hipLaunchKernelGGL(rowdot_kernel, dim3(TOK/4), dim3(256), 0, stream, d_in[17]);

  // single final writer of d_out
  hipLaunchKernelGGL(finalize, dim3(TOK/4), dim3(256), 0, stream,
                     (const int*)d_in[5], dout);
}